// Round 7
// baseline (630.381 us; speedup 1.0000x reference)
//
#include <hip/hip_runtime.h>
#include <hip/hip_bf16.h>
#include <math.h>

// Fused conv3x3(64->64) + bias + min_k + tanh(tanh()) via bf16 MFMA implicit GEMM.
// x: [16,64,256,256] f32, w: [64,64,3,3] f32, b: [64] f32, out: [16,1,256,256] f32
//
// Round 13: hardened resubmit of the NHWC-transpose design (r11/r12 hit container
// failures; source audited — all reads now provably inside ws; zrow redirect
// gains a 64-elem margin so no masked read can touch wB).
//   Design rationale (r6-r10): every stage->barrier->compute variant lands at
//   188-218us, MfmaUtil 14-17%; compiler drains vmcnt at barriers so source-level
//   pipelining is futile. The LDS staging exists ONLY to transpose NCHW->fragment
//   layout. So transpose ONCE:
//   - transpose_x: x[n][c][h][w] f32 -> xT[n][h][w][c] bf16 (128 MB in ws).
//   - conv_nhwc_mfma: A-frags = direct bf16x8 loads from xT (one 128B line = all
//     64 ch of a pixel); B-frags from global wB (L2-hot). NO LDS, NO barriers,
//     18 straight-line iters of {8 loads + 16 MFMA}; compiler free to pipeline.
//     h-OOB rows redirect into a zeroed 36KB region below xT; w-edge lanes
//     masked by cndmask.
//   - ws_size guard: needs ~128.1 MB; falls back to exact r8 kernel (188us).
// mfma_f32_16x16x32_bf16: A[m=lane&15][k=(lane>>4)*8+j], B[k=(lane>>4)*8+j][n=lane&15],
//                         C/D col=lane&15, row=(lane>>4)*4+reg (HW-verified r2-r10).

typedef __bf16 bf16x8 __attribute__((ext_vector_type(8)));
typedef float f32x4 __attribute__((ext_vector_type(4)));

#define WB_ELEMS (64 * 64 * 9)

// ws layout (bytes):
//   [0, 73728)             wB   (bf16 weights, MFMA B layout)
//   [73728, 110592)        zrow (zeroed region: 18432 bf16 = 36 KB)
//   [110592, +134217728)   xT   (NHWC bf16)
//   + 512 guard (valid-row right-edge lane reads, masked)
#define WS_ZROW_OFF   73728
#define WS_XT_OFF     110592
#define ZROW_ELEMS    18432
// OOB-row redirect: offset -(ZROW_ELEMS-64). colOff >= -64, in-row offset <= 16472,
// so redirected indices span [-18432, -1896] -> entirely inside the zeroed region.
#define ZROW_REDIR    (ZROW_ELEMS - 64)
#define WS_NEED       (110592 + 134217728 + 512)

// ---- weight prep: w[k][c][tap] -> wB[(((chunk*9+tap)*4+nt)*64+lane)*8+j] ----
// also zeroes zrow (when provided) so the conv's h-OOB redirect reads 0.
__global__ __launch_bounds__(256)
void conv_prep_w(const float* __restrict__ w, __bf16* __restrict__ wB,
                 float4* __restrict__ zrow) {
    int idx = blockIdx.x * 256 + threadIdx.x;
    if (zrow != nullptr && idx < 2304)           // 2304*16B = 36864B
        zrow[idx] = make_float4(0.f, 0.f, 0.f, 0.f);
    if (idx >= WB_ELEMS) return;
    int k   = idx / 576;
    int rem = idx - k * 576;
    int c   = rem / 9;
    int tap = rem - c * 9;
    int nt = k >> 4, m15 = k & 15;
    int chunk = c >> 5, q = (c >> 3) & 3, j = c & 7;
    int lane = (q << 4) | m15;
    wB[((((chunk * 9 + tap) * 4 + nt) * 64 + lane) << 3) + j] = (__bf16)w[idx];
}

// ---- x: NCHW f32 -> NHWC bf16. 1 px/thread: 64 coalesced plane reads, ----
// ---- one full 128-B contiguous line write per thread.                 ----
__global__ __launch_bounds__(256)
void transpose_x(const float* __restrict__ x, __bf16* __restrict__ xT) {
    const int tid   = threadIdx.x;
    const int chunk = blockIdx.x;                 // 0..255 (px chunks of 256)
    const int n     = blockIdx.y;                 // 0..15
    const int px    = (chunk << 8) | tid;
    const float* src = x + (size_t)n * 64 * 65536 + px;
    __bf16* dst = xT + ((size_t)(n * 65536 + px) << 6);
#pragma unroll
    for (int cg = 0; cg < 8; ++cg) {
        float f[8];
#pragma unroll
        for (int j = 0; j < 8; ++j)
            f[j] = src[(size_t)(cg * 8 + j) * 65536];
        bf16x8 o;
#pragma unroll
        for (int j = 0; j < 8; ++j)
            o[j] = (__bf16)f[j];
        *(bf16x8*)(dst + cg * 8) = o;
    }
}

// ---- LDS-free barrier-free conv: A from xT (NHWC), B from wB, epilogue fused ----
__global__ __launch_bounds__(256, 4)
void conv_nhwc_mfma(const __bf16* __restrict__ xT,
                    const __bf16* __restrict__ wB,
                    const float* __restrict__ b,
                    float* __restrict__ out)
{
    const int tid  = threadIdx.x;
    const int lane = tid & 63;
    const int wave = tid >> 6;
    const int m15  = lane & 15;
    const int q    = lane >> 4;

    // XCD-aware bijective remap (r8-verified: FETCH 503->131 MB)
    const int lin = (int)blockIdx.x + ((int)blockIdx.y << 4) + ((int)blockIdx.z << 8);
    const int nl  = ((lin & 7) << 9) | (lin >> 3);
    const int n   = nl >> 8;
    const int h0  = ((nl >> 4) & 15) << 4;
    const int w0  = (nl & 15) << 4;

    // per-row element indices into xT; h-OOB rows redirect into the zeroed region
    int rowIdx[6];
#pragma unroll
    for (int rr = 0; rr < 6; ++rr) {
        const int gh = h0 + wave * 4 + rr - 1;
        rowIdx[rr] = ((unsigned)gh < 256u) ? (n * 256 + gh) * 16384 : -ZROW_REDIR;
    }
    // per-lane column offset: pixel (w0 + m15 - 1), channels q*8..+7
    const int colOff = (w0 + m15 - 1) * 64 + q * 8;

    // w-edge masks: s=0 invalid only for (w0==0, m15==0); s=2 only (w0==240, m15==15)
    const bool wv0 = !(w0 == 0   && m15 == 0);
    const bool wv2 = !(w0 == 240 && m15 == 15);
    bf16x8 z8;
#pragma unroll
    for (int j = 0; j < 8; ++j) z8[j] = (__bf16)0.f;

    f32x4 acc[4][4];  // [mt][nt]
#pragma unroll
    for (int mt = 0; mt < 4; ++mt)
#pragma unroll
        for (int nt = 0; nt < 4; ++nt)
            acc[mt][nt] = (f32x4){0.f, 0.f, 0.f, 0.f};

#pragma unroll
    for (int r = 0; r < 3; ++r) {
#pragma unroll
        for (int s = 0; s < 3; ++s) {
            const int tap = r * 3 + s;
#pragma unroll
            for (int kc = 0; kc < 2; ++kc) {
                bf16x8 bf4[4], a4[4];
#pragma unroll
                for (int nt = 0; nt < 4; ++nt)
                    bf4[nt] = *(const bf16x8*)
                        &wB[kc * 18432 + (((tap << 2) | nt) << 9) + (lane << 3)];
#pragma unroll
                for (int mt = 0; mt < 4; ++mt) {
                    bf16x8 a = *(const bf16x8*)
                        &xT[rowIdx[mt + r] + colOff + s * 64 + kc * 32];
                    if (s == 0) a = wv0 ? a : z8;
                    if (s == 2) a = wv2 ? a : z8;
                    a4[mt] = a;
                }
                __builtin_amdgcn_s_setprio(1);
#pragma unroll
                for (int mt = 0; mt < 4; ++mt)
#pragma unroll
                    for (int nt = 0; nt < 4; ++nt)
                        acc[mt][nt] = __builtin_amdgcn_mfma_f32_16x16x32_bf16(
                            a4[mt], bf4[nt], acc[mt][nt], 0, 0, 0);
                __builtin_amdgcn_s_setprio(0);
            }
        }
    }

    // ---- epilogue: +bias, min over 64 k, tanh(tanh), store (verified r2-r10) ----
    float bias[4];
#pragma unroll
    for (int nt = 0; nt < 4; ++nt) bias[nt] = b[nt * 16 + m15];

#pragma unroll
    for (int mt = 0; mt < 4; ++mt) {
        float mv[4];
#pragma unroll
        for (int reg = 0; reg < 4; ++reg) {
            float v2 = acc[mt][0][reg] + bias[0];
            v2 = fminf(v2, acc[mt][1][reg] + bias[1]);
            v2 = fminf(v2, acc[mt][2][reg] + bias[2]);
            v2 = fminf(v2, acc[mt][3][reg] + bias[3]);
            v2 = fminf(v2, __shfl_xor(v2, 1));
            v2 = fminf(v2, __shfl_xor(v2, 2));
            v2 = fminf(v2, __shfl_xor(v2, 4));
            v2 = fminf(v2, __shfl_xor(v2, 8));
            mv[reg] = v2;
        }
        const int r2 = lane & 3;
        float v2 = mv[0];
        v2 = (r2 == 1) ? mv[1] : v2;
        v2 = (r2 == 2) ? mv[2] : v2;
        v2 = (r2 == 3) ? mv[3] : v2;
        v2 = tanhf(tanhf(v2));
        if (m15 < 4) {
            const int gh = h0 + wave * 4 + mt;
            const int gw = w0 + q * 4 + r2;
            out[((size_t)n * 256 + gh) * 256 + gw] = v2;
        }
    }
}

// ==================== fallback: exact r8 kernel (best LDS-staged, 188 us) ====================
#define SA_PX   40
#define SA_ROW  (20 * SA_PX)

__global__ __launch_bounds__(256, 3)
void conv_min_tanh_lds(const float* __restrict__ x,
                       const __bf16* __restrict__ wB,
                       const float* __restrict__ b,
                       float* __restrict__ out)
{
    __shared__ __attribute__((aligned(16))) __bf16 sA[18 * SA_ROW];

    const int tid  = threadIdx.x;
    const int lane = tid & 63;
    const int wave = tid >> 6;
    const int m15  = lane & 15;
    const int q    = lane >> 4;

    const int lin = (int)blockIdx.x + ((int)blockIdx.y << 4) + ((int)blockIdx.z << 8);
    const int nl  = ((lin & 7) << 9) | (lin >> 3);
    const int n   = nl >> 8;
    const int h0  = ((nl >> 4) & 15) << 4;
    const int w0  = (nl & 15) << 4;

    f32x4 acc[4][4];
#pragma unroll
    for (int mt = 0; mt < 4; ++mt)
#pragma unroll
        for (int nt = 0; nt < 4; ++nt)
            acc[mt][nt] = (f32x4){0.f, 0.f, 0.f, 0.f};

#pragma unroll 1
    for (int chunk = 0; chunk < 2; ++chunk) {
        if (chunk) __syncthreads();

        for (int slot = tid; slot < 360; slot += 256) {
            const int row  = slot / 20;
            const int rem  = slot - row * 20;
            const int span = rem >> 2;
            const int cg   = rem & 3;
            const int gh   = h0 + row - 1;
            const int gw0  = w0 - 1 + span * 4;

            f32x4 v[8];
            if ((unsigned)gh < 256u) {
                const float* src = x + (size_t)(n * 64 + chunk * 32 + cg * 8) * 65536
                                     + (size_t)gh * 256;
                if (gw0 >= 0 && gw0 <= 252) {
#pragma unroll
                    for (int j = 0; j < 8; ++j)
                        v[j] = *(const f32x4*)&src[(size_t)j * 65536 + gw0];
                } else {
#pragma unroll
                    for (int j = 0; j < 8; ++j)
#pragma unroll
                        for (int i = 0; i < 4; ++i) {
                            const int gw = gw0 + i;
                            v[j][i] = ((unsigned)gw < 256u) ? src[(size_t)j * 65536 + gw] : 0.f;
                        }
                }
            } else {
#pragma unroll
                for (int j = 0; j < 8; ++j)
                    v[j] = (f32x4){0.f, 0.f, 0.f, 0.f};
            }
            __bf16* wp = &sA[row * SA_ROW + (span * 4) * SA_PX + cg * 8];
#pragma unroll
            for (int i = 0; i < 4; ++i) {
                bf16x8 o;
                o[0] = (__bf16)v[0][i]; o[1] = (__bf16)v[1][i];
                o[2] = (__bf16)v[2][i]; o[3] = (__bf16)v[3][i];
                o[4] = (__bf16)v[4][i]; o[5] = (__bf16)v[5][i];
                o[6] = (__bf16)v[6][i]; o[7] = (__bf16)v[7][i];
                *(bf16x8*)&wp[i * SA_PX] = o;
            }
        }
        __syncthreads();

        const __bf16* wBc = wB + chunk * 18432;
#pragma unroll
        for (int r = 0; r < 3; ++r) {
#pragma unroll
            for (int s2 = 0; s2 < 3; ++s2) {
                const int tap = r * 3 + s2;
                bf16x8 bf4[4], a4[4];
#pragma unroll
                for (int nt = 0; nt < 4; ++nt)
                    bf4[nt] = *(const bf16x8*)&wBc[(((tap << 2) | nt) << 9) | (lane << 3)];
#pragma unroll
                for (int mt = 0; mt < 4; ++mt)
                    a4[mt] = *(const bf16x8*)
                        &sA[(wave * 4 + mt + r) * SA_ROW + (m15 + s2) * SA_PX + q * 8];
#pragma unroll
                for (int mt = 0; mt < 4; ++mt)
#pragma unroll
                    for (int nt = 0; nt < 4; ++nt)
                        acc[mt][nt] = __builtin_amdgcn_mfma_f32_16x16x32_bf16(
                            a4[mt], bf4[nt], acc[mt][nt], 0, 0, 0);
            }
        }
    }

    float bias[4];
#pragma unroll
    for (int nt = 0; nt < 4; ++nt) bias[nt] = b[nt * 16 + m15];

#pragma unroll
    for (int mt = 0; mt < 4; ++mt) {
        float mv[4];
#pragma unroll
        for (int reg = 0; reg < 4; ++reg) {
            float v2 = acc[mt][0][reg] + bias[0];
            v2 = fminf(v2, acc[mt][1][reg] + bias[1]);
            v2 = fminf(v2, acc[mt][2][reg] + bias[2]);
            v2 = fminf(v2, acc[mt][3][reg] + bias[3]);
            v2 = fminf(v2, __shfl_xor(v2, 1));
            v2 = fminf(v2, __shfl_xor(v2, 2));
            v2 = fminf(v2, __shfl_xor(v2, 4));
            v2 = fminf(v2, __shfl_xor(v2, 8));
            mv[reg] = v2;
        }
        const int r2 = lane & 3;
        float v2 = mv[0];
        v2 = (r2 == 1) ? mv[1] : v2;
        v2 = (r2 == 2) ? mv[2] : v2;
        v2 = (r2 == 3) ? mv[3] : v2;
        v2 = tanhf(tanhf(v2));
        if (m15 < 4) {
            const int pix = q * 4 + r2;
            const int gh  = h0 + wave * 4 + mt;
            const int gw  = w0 + pix;
            out[((size_t)n * 256 + gh) * 256 + gw] = v2;
        }
    }
}

extern "C" void kernel_launch(void* const* d_in, const int* in_sizes, int n_in,
                              void* d_out, int out_size, void* d_ws, size_t ws_size,
                              hipStream_t stream) {
    const float* x = (const float*)d_in[0];
    const float* w = (const float*)d_in[1];
    const float* b = (const float*)d_in[2];
    float* out = (float*)d_out;
    __bf16* wB = (__bf16*)d_ws;

    if (ws_size >= (size_t)WS_NEED) {
        float4* zrow = (float4*)((char*)d_ws + WS_ZROW_OFF);
        __bf16* xT   = (__bf16*)((char*)d_ws + WS_XT_OFF);
        conv_prep_w<<<dim3(144), dim3(256), 0, stream>>>(w, wB, zrow);
        transpose_x<<<dim3(256, 16), dim3(256), 0, stream>>>(x, xT);
        conv_nhwc_mfma<<<dim3(16, 16, 16), dim3(256), 0, stream>>>(xT, wB, b, out);
    } else {
        conv_prep_w<<<dim3(144), dim3(256), 0, stream>>>(w, wB, nullptr);
        conv_min_tanh_lds<<<dim3(16, 16, 16), dim3(256), 0, stream>>>(x, wB, b, out);
    }
}

// Round 8
// 566.747 us; speedup vs baseline: 1.1123x; 1.1123x over previous
//
#include <hip/hip_runtime.h>
#include <hip/hip_bf16.h>
#include <math.h>

// Fused conv3x3(64->64) + bias + min_k + tanh(tanh()) via bf16 MFMA implicit GEMM.
// x: [16,64,256,256] f32, w: [64,64,3,3] f32, b: [64] f32, out: [16,1,256,256] f32
//
// Round 14: r13 ran; conv spilled (VGPR_Count=64, WRITE_SIZE=217MB -> the
// (256,4) unified-register cap strangled it exactly like r7). ONE change:
// __launch_bounds__(256,3) on conv_nhwc_mfma (170-reg cap; live-set shape
// identical to the r8 kernel that was spill-free at this bound).
//   Design (r11-r13): LDS staging existed only to transpose NCHW->fragment
//   layout; transpose ONCE instead.
//   - transpose_x: x[n][c][h][w] f32 -> xT[n][h][w][c] bf16 (128 MB in ws).
//   - conv_nhwc_mfma: A-frags = direct bf16x8 loads from xT (one 128B line =
//     all 64 ch of a pixel); B-frags from global wB (L2-hot). NO LDS, NO
//     barriers; 18 straight-line iters of {8 loads + 16 MFMA}.
//     h-OOB rows redirect into a zeroed 36KB region below xT; w-edge lanes
//     masked by cndmask.
//   - ws_size guard: needs ~128.1 MB; falls back to exact r8 kernel (188us).
// mfma_f32_16x16x32_bf16: A[m=lane&15][k=(lane>>4)*8+j], B[k=(lane>>4)*8+j][n=lane&15],
//                         C/D col=lane&15, row=(lane>>4)*4+reg (HW-verified r2-r13).

typedef __bf16 bf16x8 __attribute__((ext_vector_type(8)));
typedef float f32x4 __attribute__((ext_vector_type(4)));

#define WB_ELEMS (64 * 64 * 9)

// ws layout (bytes):
//   [0, 73728)             wB   (bf16 weights, MFMA B layout)
//   [73728, 110592)        zrow (zeroed region: 18432 bf16 = 36 KB)
//   [110592, +134217728)   xT   (NHWC bf16)
//   + 512 guard (valid-row right-edge lane reads, masked)
#define WS_ZROW_OFF   73728
#define WS_XT_OFF     110592
#define ZROW_ELEMS    18432
// OOB-row redirect: offset -(ZROW_ELEMS-64). colOff >= -64, in-row offset <= 16472,
// so redirected indices span [-18432, -1896] -> entirely inside the zeroed region.
#define ZROW_REDIR    (ZROW_ELEMS - 64)
#define WS_NEED       (110592 + 134217728 + 512)

// ---- weight prep: w[k][c][tap] -> wB[(((chunk*9+tap)*4+nt)*64+lane)*8+j] ----
// also zeroes zrow (when provided) so the conv's h-OOB redirect reads 0.
__global__ __launch_bounds__(256)
void conv_prep_w(const float* __restrict__ w, __bf16* __restrict__ wB,
                 float4* __restrict__ zrow) {
    int idx = blockIdx.x * 256 + threadIdx.x;
    if (zrow != nullptr && idx < 2304)           // 2304*16B = 36864B
        zrow[idx] = make_float4(0.f, 0.f, 0.f, 0.f);
    if (idx >= WB_ELEMS) return;
    int k   = idx / 576;
    int rem = idx - k * 576;
    int c   = rem / 9;
    int tap = rem - c * 9;
    int nt = k >> 4, m15 = k & 15;
    int chunk = c >> 5, q = (c >> 3) & 3, j = c & 7;
    int lane = (q << 4) | m15;
    wB[((((chunk * 9 + tap) * 4 + nt) * 64 + lane) << 3) + j] = (__bf16)w[idx];
}

// ---- x: NCHW f32 -> NHWC bf16. 1 px/thread: 64 coalesced plane reads, ----
// ---- one full 128-B contiguous line write per thread.                 ----
__global__ __launch_bounds__(256)
void transpose_x(const float* __restrict__ x, __bf16* __restrict__ xT) {
    const int tid   = threadIdx.x;
    const int chunk = blockIdx.x;                 // 0..255 (px chunks of 256)
    const int n     = blockIdx.y;                 // 0..15
    const int px    = (chunk << 8) | tid;
    const float* src = x + (size_t)n * 64 * 65536 + px;
    __bf16* dst = xT + ((size_t)(n * 65536 + px) << 6);
#pragma unroll
    for (int cg = 0; cg < 8; ++cg) {
        float f[8];
#pragma unroll
        for (int j = 0; j < 8; ++j)
            f[j] = src[(size_t)(cg * 8 + j) * 65536];
        bf16x8 o;
#pragma unroll
        for (int j = 0; j < 8; ++j)
            o[j] = (__bf16)f[j];
        *(bf16x8*)(dst + cg * 8) = o;
    }
}

// ---- LDS-free barrier-free conv: A from xT (NHWC), B from wB, epilogue fused ----
__global__ __launch_bounds__(256, 3)
void conv_nhwc_mfma(const __bf16* __restrict__ xT,
                    const __bf16* __restrict__ wB,
                    const float* __restrict__ b,
                    float* __restrict__ out)
{
    const int tid  = threadIdx.x;
    const int lane = tid & 63;
    const int wave = tid >> 6;
    const int m15  = lane & 15;
    const int q    = lane >> 4;

    // XCD-aware bijective remap (r8-verified: FETCH 503->131 MB)
    const int lin = (int)blockIdx.x + ((int)blockIdx.y << 4) + ((int)blockIdx.z << 8);
    const int nl  = ((lin & 7) << 9) | (lin >> 3);
    const int n   = nl >> 8;
    const int h0  = ((nl >> 4) & 15) << 4;
    const int w0  = (nl & 15) << 4;

    // per-row element indices into xT; h-OOB rows redirect into the zeroed region
    int rowIdx[6];
#pragma unroll
    for (int rr = 0; rr < 6; ++rr) {
        const int gh = h0 + wave * 4 + rr - 1;
        rowIdx[rr] = ((unsigned)gh < 256u) ? (n * 256 + gh) * 16384 : -ZROW_REDIR;
    }
    // per-lane column offset: pixel (w0 + m15 - 1), channels q*8..+7
    const int colOff = (w0 + m15 - 1) * 64 + q * 8;

    // w-edge masks: s=0 invalid only for (w0==0, m15==0); s=2 only (w0==240, m15==15)
    const bool wv0 = !(w0 == 0   && m15 == 0);
    const bool wv2 = !(w0 == 240 && m15 == 15);
    bf16x8 z8;
#pragma unroll
    for (int j = 0; j < 8; ++j) z8[j] = (__bf16)0.f;

    f32x4 acc[4][4];  // [mt][nt]
#pragma unroll
    for (int mt = 0; mt < 4; ++mt)
#pragma unroll
        for (int nt = 0; nt < 4; ++nt)
            acc[mt][nt] = (f32x4){0.f, 0.f, 0.f, 0.f};

#pragma unroll
    for (int r = 0; r < 3; ++r) {
#pragma unroll
        for (int s = 0; s < 3; ++s) {
            const int tap = r * 3 + s;
#pragma unroll
            for (int kc = 0; kc < 2; ++kc) {
                bf16x8 bf4[4], a4[4];
#pragma unroll
                for (int nt = 0; nt < 4; ++nt)
                    bf4[nt] = *(const bf16x8*)
                        &wB[kc * 18432 + (((tap << 2) | nt) << 9) + (lane << 3)];
#pragma unroll
                for (int mt = 0; mt < 4; ++mt) {
                    bf16x8 a = *(const bf16x8*)
                        &xT[rowIdx[mt + r] + colOff + s * 64 + kc * 32];
                    if (s == 0) a = wv0 ? a : z8;
                    if (s == 2) a = wv2 ? a : z8;
                    a4[mt] = a;
                }
                __builtin_amdgcn_s_setprio(1);
#pragma unroll
                for (int mt = 0; mt < 4; ++mt)
#pragma unroll
                    for (int nt = 0; nt < 4; ++nt)
                        acc[mt][nt] = __builtin_amdgcn_mfma_f32_16x16x32_bf16(
                            a4[mt], bf4[nt], acc[mt][nt], 0, 0, 0);
                __builtin_amdgcn_s_setprio(0);
            }
        }
    }

    // ---- epilogue: +bias, min over 64 k, tanh(tanh), store (verified r2-r13) ----
    float bias[4];
#pragma unroll
    for (int nt = 0; nt < 4; ++nt) bias[nt] = b[nt * 16 + m15];

#pragma unroll
    for (int mt = 0; mt < 4; ++mt) {
        float mv[4];
#pragma unroll
        for (int reg = 0; reg < 4; ++reg) {
            float v2 = acc[mt][0][reg] + bias[0];
            v2 = fminf(v2, acc[mt][1][reg] + bias[1]);
            v2 = fminf(v2, acc[mt][2][reg] + bias[2]);
            v2 = fminf(v2, acc[mt][3][reg] + bias[3]);
            v2 = fminf(v2, __shfl_xor(v2, 1));
            v2 = fminf(v2, __shfl_xor(v2, 2));
            v2 = fminf(v2, __shfl_xor(v2, 4));
            v2 = fminf(v2, __shfl_xor(v2, 8));
            mv[reg] = v2;
        }
        const int r2 = lane & 3;
        float v2 = mv[0];
        v2 = (r2 == 1) ? mv[1] : v2;
        v2 = (r2 == 2) ? mv[2] : v2;
        v2 = (r2 == 3) ? mv[3] : v2;
        v2 = tanhf(tanhf(v2));
        if (m15 < 4) {
            const int gh = h0 + wave * 4 + mt;
            const int gw = w0 + q * 4 + r2;
            out[((size_t)n * 256 + gh) * 256 + gw] = v2;
        }
    }
}

// ==================== fallback: exact r8 kernel (best LDS-staged, 188 us) ====================
#define SA_PX   40
#define SA_ROW  (20 * SA_PX)

__global__ __launch_bounds__(256, 3)
void conv_min_tanh_lds(const float* __restrict__ x,
                       const __bf16* __restrict__ wB,
                       const float* __restrict__ b,
                       float* __restrict__ out)
{
    __shared__ __attribute__((aligned(16))) __bf16 sA[18 * SA_ROW];

    const int tid  = threadIdx.x;
    const int lane = tid & 63;
    const int wave = tid >> 6;
    const int m15  = lane & 15;
    const int q    = lane >> 4;

    const int lin = (int)blockIdx.x + ((int)blockIdx.y << 4) + ((int)blockIdx.z << 8);
    const int nl  = ((lin & 7) << 9) | (lin >> 3);
    const int n   = nl >> 8;
    const int h0  = ((nl >> 4) & 15) << 4;
    const int w0  = (nl & 15) << 4;

    f32x4 acc[4][4];
#pragma unroll
    for (int mt = 0; mt < 4; ++mt)
#pragma unroll
        for (int nt = 0; nt < 4; ++nt)
            acc[mt][nt] = (f32x4){0.f, 0.f, 0.f, 0.f};

#pragma unroll 1
    for (int chunk = 0; chunk < 2; ++chunk) {
        if (chunk) __syncthreads();

        for (int slot = tid; slot < 360; slot += 256) {
            const int row  = slot / 20;
            const int rem  = slot - row * 20;
            const int span = rem >> 2;
            const int cg   = rem & 3;
            const int gh   = h0 + row - 1;
            const int gw0  = w0 - 1 + span * 4;

            f32x4 v[8];
            if ((unsigned)gh < 256u) {
                const float* src = x + (size_t)(n * 64 + chunk * 32 + cg * 8) * 65536
                                     + (size_t)gh * 256;
                if (gw0 >= 0 && gw0 <= 252) {
#pragma unroll
                    for (int j = 0; j < 8; ++j)
                        v[j] = *(const f32x4*)&src[(size_t)j * 65536 + gw0];
                } else {
#pragma unroll
                    for (int j = 0; j < 8; ++j)
#pragma unroll
                        for (int i = 0; i < 4; ++i) {
                            const int gw = gw0 + i;
                            v[j][i] = ((unsigned)gw < 256u) ? src[(size_t)j * 65536 + gw] : 0.f;
                        }
                }
            } else {
#pragma unroll
                for (int j = 0; j < 8; ++j)
                    v[j] = (f32x4){0.f, 0.f, 0.f, 0.f};
            }
            __bf16* wp = &sA[row * SA_ROW + (span * 4) * SA_PX + cg * 8];
#pragma unroll
            for (int i = 0; i < 4; ++i) {
                bf16x8 o;
                o[0] = (__bf16)v[0][i]; o[1] = (__bf16)v[1][i];
                o[2] = (__bf16)v[2][i]; o[3] = (__bf16)v[3][i];
                o[4] = (__bf16)v[4][i]; o[5] = (__bf16)v[5][i];
                o[6] = (__bf16)v[6][i]; o[7] = (__bf16)v[7][i];
                *(bf16x8*)&wp[i * SA_PX] = o;
            }
        }
        __syncthreads();

        const __bf16* wBc = wB + chunk * 18432;
#pragma unroll
        for (int r = 0; r < 3; ++r) {
#pragma unroll
            for (int s2 = 0; s2 < 3; ++s2) {
                const int tap = r * 3 + s2;
                bf16x8 bf4[4], a4[4];
#pragma unroll
                for (int nt = 0; nt < 4; ++nt)
                    bf4[nt] = *(const bf16x8*)&wBc[(((tap << 2) | nt) << 9) | (lane << 3)];
#pragma unroll
                for (int mt = 0; mt < 4; ++mt)
                    a4[mt] = *(const bf16x8*)
                        &sA[(wave * 4 + mt + r) * SA_ROW + (m15 + s2) * SA_PX + q * 8];
#pragma unroll
                for (int mt = 0; mt < 4; ++mt)
#pragma unroll
                    for (int nt = 0; nt < 4; ++nt)
                        acc[mt][nt] = __builtin_amdgcn_mfma_f32_16x16x32_bf16(
                            a4[mt], bf4[nt], acc[mt][nt], 0, 0, 0);
            }
        }
    }

    float bias[4];
#pragma unroll
    for (int nt = 0; nt < 4; ++nt) bias[nt] = b[nt * 16 + m15];

#pragma unroll
    for (int mt = 0; mt < 4; ++mt) {
        float mv[4];
#pragma unroll
        for (int reg = 0; reg < 4; ++reg) {
            float v2 = acc[mt][0][reg] + bias[0];
            v2 = fminf(v2, acc[mt][1][reg] + bias[1]);
            v2 = fminf(v2, acc[mt][2][reg] + bias[2]);
            v2 = fminf(v2, acc[mt][3][reg] + bias[3]);
            v2 = fminf(v2, __shfl_xor(v2, 1));
            v2 = fminf(v2, __shfl_xor(v2, 2));
            v2 = fminf(v2, __shfl_xor(v2, 4));
            v2 = fminf(v2, __shfl_xor(v2, 8));
            mv[reg] = v2;
        }
        const int r2 = lane & 3;
        float v2 = mv[0];
        v2 = (r2 == 1) ? mv[1] : v2;
        v2 = (r2 == 2) ? mv[2] : v2;
        v2 = (r2 == 3) ? mv[3] : v2;
        v2 = tanhf(tanhf(v2));
        if (m15 < 4) {
            const int pix = q * 4 + r2;
            const int gh  = h0 + wave * 4 + mt;
            const int gw  = w0 + pix;
            out[((size_t)n * 256 + gh) * 256 + gw] = v2;
        }
    }
}

extern "C" void kernel_launch(void* const* d_in, const int* in_sizes, int n_in,
                              void* d_out, int out_size, void* d_ws, size_t ws_size,
                              hipStream_t stream) {
    const float* x = (const float*)d_in[0];
    const float* w = (const float*)d_in[1];
    const float* b = (const float*)d_in[2];
    float* out = (float*)d_out;
    __bf16* wB = (__bf16*)d_ws;

    if (ws_size >= (size_t)WS_NEED) {
        float4* zrow = (float4*)((char*)d_ws + WS_ZROW_OFF);
        __bf16* xT   = (__bf16*)((char*)d_ws + WS_XT_OFF);
        conv_prep_w<<<dim3(144), dim3(256), 0, stream>>>(w, wB, zrow);
        transpose_x<<<dim3(256, 16), dim3(256), 0, stream>>>(x, xT);
        conv_nhwc_mfma<<<dim3(16, 16, 16), dim3(256), 0, stream>>>(xT, wB, b, out);
    } else {
        conv_prep_w<<<dim3(144), dim3(256), 0, stream>>>(w, wB, nullptr);
        conv_min_tanh_lds<<<dim3(16, 16, 16), dim3(256), 0, stream>>>(x, wB, b, out);
    }
}